// Round 1
// baseline (833.250 us; speedup 1.0000x reference)
//
#include <hip/hip_runtime.h>
#include <hip/hip_bf16.h>
#include <math.h>

// Problem constants
#define HID   2048
#define NEXP  8
#define IMOE  1408
#define ISH   5632
#define NTOK  1024
#define NASSIGN 2048   // NTOK * TOP_K

typedef __bf16 bf16;
typedef __bf16 bf16x8 __attribute__((ext_vector_type(8)));
typedef float  f32x4  __attribute__((ext_vector_type(4)));

// ---------------------------------------------------------------------------
// Router: logits = x @ gate_w^T (8), shared gate logit (1).
// top-2 of softmax renormalized == sigmoid(l0 - l1). One block per token.
// ---------------------------------------------------------------------------
__global__ __launch_bounds__(256) void router_kernel(
    const float* __restrict__ x, const float* __restrict__ gate_w,
    const float* __restrict__ sgate_w, float* __restrict__ sg,
    int2* __restrict__ tk_idx, float2* __restrict__ tk_w)
{
  const int t = blockIdx.x;
  const float* xr = x + (long)t * HID;
  float p[9];
#pragma unroll
  for (int i = 0; i < 9; i++) p[i] = 0.f;
  for (int c = threadIdx.x; c < HID; c += 256) {
    float xv = xr[c];
#pragma unroll
    for (int e = 0; e < 8; e++) p[e] += xv * gate_w[e * HID + c];
    p[8] += xv * sgate_w[c];
  }
#pragma unroll
  for (int i = 0; i < 9; i++)
    for (int off = 32; off > 0; off >>= 1)
      p[i] += __shfl_xor(p[i], off, 64);
  __shared__ float red[4][9];
  const int wave = threadIdx.x >> 6, lane = threadIdx.x & 63;
  if (lane == 0)
    for (int i = 0; i < 9; i++) red[wave][i] = p[i];
  __syncthreads();
  if (threadIdx.x == 0) {
    float l[9];
    for (int i = 0; i < 9; i++)
      l[i] = red[0][i] + red[1][i] + red[2][i] + red[3][i];
    int i0 = 0;
    for (int e = 1; e < 8; e++) if (l[e] > l[i0]) i0 = e;   // ties -> lowest idx
    int i1 = -1;
    for (int e = 0; e < 8; e++) {
      if (e == i0) continue;
      if (i1 < 0 || l[e] > l[i1]) i1 = e;
    }
    float w0 = 1.f / (1.f + __expf(l[i1] - l[i0]));
    tk_idx[t] = make_int2(i0, i1);
    tk_w[t]   = make_float2(w0, 1.f - w0);
    sg[t]     = 1.f / (1.f + __expf(-l[8]));
  }
}

// ---------------------------------------------------------------------------
// Scatter assignments (token,slot) into expert-sorted compact lists.
// Single block. offs[9] = CSR offsets per expert.
// ---------------------------------------------------------------------------
__global__ __launch_bounds__(256) void scatter_kernel(
    const int2* __restrict__ tk_idx, const float2* __restrict__ tk_w,
    int* __restrict__ offs, int* __restrict__ s_tok, float* __restrict__ s_wgt)
{
  __shared__ int cnt[8], pos[8];
  if (threadIdx.x < 8) cnt[threadIdx.x] = 0;
  __syncthreads();
  for (int a = threadIdx.x; a < NASSIGN; a += 256) {
    int2 ii = tk_idx[a >> 1];
    int e = (a & 1) ? ii.y : ii.x;
    atomicAdd(&cnt[e], 1);
  }
  __syncthreads();
  if (threadIdx.x == 0) {
    int s = 0;
    for (int e = 0; e < 8; e++) { offs[e] = s; pos[e] = s; s += cnt[e]; }
    offs[8] = s;
  }
  __syncthreads();
  for (int a = threadIdx.x; a < NASSIGN; a += 256) {
    int t = a >> 1;
    int2 ii = tk_idx[t];
    float2 ww = tk_w[t];
    int   e = (a & 1) ? ii.y : ii.x;
    float w = (a & 1) ? ww.y : ww.x;
    int pp = atomicAdd(&pos[e], 1);
    s_tok[pp] = t;
    s_wgt[pp] = w;
  }
}

// ---------------------------------------------------------------------------
// Fused gate_up GEMM + SiLU*mul epilogue.  C[m,n] = silu(X.Wg^T) * (X.Wu^T)
// A = fp32 token rows (direct or gathered), W rows are K-contiguous (B^T GEMM).
// BM x 64 output tile of h; 4 waves in 2x2; BK=32; 16x16x32 bf16 MFMA.
// ---------------------------------------------------------------------------
template<int BM, bool GROUPED>
__global__ __launch_bounds__(256) void gemm_gu(
    const float* __restrict__ X,
    const float* __restrict__ Wg_base,
    long expert_stride,   // elems between expert weight blocks (0 if shared)
    long up_off,          // elems from gate row block to up row block (I*K)
    int K,
    bf16* __restrict__ Hout, int hstride,
    const int* __restrict__ offs, const int* __restrict__ s_tok)
{
  static_assert(BM == 64 || BM == 128, "BM");
  constexpr int BN = 64;
  const int n0 = blockIdx.x * BN;
  const int e  = GROUPED ? blockIdx.z : 0;
  int m_base, m_end;
  if (GROUPED) {
    m_base = offs[e] + blockIdx.y * BM;
    m_end  = offs[e + 1];
    if (m_base >= m_end) return;
  } else {
    m_base = blockIdx.y * BM;
    m_end  = NTOK;
  }
  const float* Wg = Wg_base + (long)e * expert_stride;
  const float* Wu = Wg + up_off;

  constexpr int LDT = 40;  // bf16 elems per LDS row (80B: b128-aligned, low conflicts)
  __shared__ __attribute__((aligned(16))) bf16 As[BM * LDT];
  __shared__ __attribute__((aligned(16))) bf16 Bs[128 * LDT]; // [0..63]=gate [64..127]=up
  __shared__ int rowtok[BM];

  const int tid = threadIdx.x;
  if (tid < BM) {
    int r = m_base + tid;
    if (GROUPED) rowtok[tid] = (r < m_end) ? s_tok[r] : -1;
    else         rowtok[tid] = r;
  }

  const int wave = tid >> 6, lane = tid & 63;
  const int wm = wave >> 1, wn = wave & 1;       // 2x2 wave grid
  constexpr int AF = BM / 32;                    // A frags per wave
  f32x4 accg[AF][2], accu[AF][2];
#pragma unroll
  for (int i = 0; i < AF; i++)
#pragma unroll
    for (int j = 0; j < 2; j++) {
      accg[i][j] = f32x4{0.f, 0.f, 0.f, 0.f};
      accu[i][j] = f32x4{0.f, 0.f, 0.f, 0.f};
    }

  const int ar = tid >> 3, ac = (tid & 7) * 4;   // 32 rows x 8 float4 per pass
  __syncthreads();  // rowtok visible

  for (int k0 = 0; k0 < K; k0 += 32) {
    // stage A (fp32 -> bf16)
#pragma unroll
    for (int p = 0; p < BM / 32; p++) {
      int r = p * 32 + ar;
      int tok = rowtok[r];
      float4 v = make_float4(0.f, 0.f, 0.f, 0.f);
      if (tok >= 0) v = *(const float4*)&X[(long)tok * K + k0 + ac];
      bf16* d = &As[r * LDT + ac];
      d[0] = (bf16)v.x; d[1] = (bf16)v.y; d[2] = (bf16)v.z; d[3] = (bf16)v.w;
    }
    // stage B: gate rows then up rows
#pragma unroll
    for (int p = 0; p < 4; p++) {
      int r = p * 32 + ar;
      const float* src = (r < 64) ? &Wg[(long)(n0 + r) * K + k0 + ac]
                                  : &Wu[(long)(n0 + r - 64) * K + k0 + ac];
      float4 v = *(const float4*)src;
      bf16* d = &Bs[r * LDT + ac];
      d[0] = (bf16)v.x; d[1] = (bf16)v.y; d[2] = (bf16)v.z; d[3] = (bf16)v.w;
    }
    __syncthreads();
    const int fr = lane & 15, fk = (lane >> 4) * 8;
    bf16x8 a[AF], bg[2], bu[2];
#pragma unroll
    for (int i = 0; i < AF; i++)
      a[i] = *(const bf16x8*)&As[(wm * (AF * 16) + i * 16 + fr) * LDT + fk];
#pragma unroll
    for (int j = 0; j < 2; j++) {
      bg[j] = *(const bf16x8*)&Bs[(wn * 32 + j * 16 + fr) * LDT + fk];
      bu[j] = *(const bf16x8*)&Bs[(64 + wn * 32 + j * 16 + fr) * LDT + fk];
    }
#pragma unroll
    for (int i = 0; i < AF; i++)
#pragma unroll
      for (int j = 0; j < 2; j++) {
        accg[i][j] = __builtin_amdgcn_mfma_f32_16x16x32_bf16(a[i], bg[j], accg[i][j], 0, 0, 0);
        accu[i][j] = __builtin_amdgcn_mfma_f32_16x16x32_bf16(a[i], bu[j], accu[i][j], 0, 0, 0);
      }
    __syncthreads();
  }
  // epilogue: h = silu(g) * u  (C/D layout: row=(lane>>4)*4+r, col=lane&15)
#pragma unroll
  for (int i = 0; i < AF; i++)
#pragma unroll
    for (int j = 0; j < 2; j++)
#pragma unroll
      for (int r = 0; r < 4; r++) {
        int row = wm * (AF * 16) + i * 16 + (lane >> 4) * 4 + r;
        int grow = m_base + row;
        if (GROUPED && grow >= m_end) continue;
        int col = wn * 32 + j * 16 + (lane & 15);
        float g = accg[i][j][r], u = accu[i][j][r];
        float h = g / (1.f + __expf(-g)) * u;
        Hout[(long)grow * hstride + n0 + col] = (bf16)h;
      }
}

// ---------------------------------------------------------------------------
// Down GEMM: out[target(m), n] += scale(m) * (H . W^T)[m,n]
// A = bf16 compact rows (ws). 64x128 tile, 4 waves 2x2, BK=32. atomicAdd epilogue.
// !GROUPED: split-K via blockIdx.z (KSPLIT).  GROUPED: blockIdx.z = expert.
// ---------------------------------------------------------------------------
template<bool GROUPED, int KSPLIT>
__global__ __launch_bounds__(256) void gemm_down(
    const bf16* __restrict__ Hin, int K,
    const float* __restrict__ W_base, long expert_stride,
    float* __restrict__ Out,
    const float* __restrict__ scale,
    const int* __restrict__ offs, const int* __restrict__ s_tok)
{
  constexpr int BM = 64, BN = 128;
  const int n0 = blockIdx.x * BN;
  int e = 0, m_base, m_end, k_lo, k_hi;
  if (GROUPED) {
    e = blockIdx.z;
    m_base = offs[e] + blockIdx.y * BM;
    m_end  = offs[e + 1];
    if (m_base >= m_end) return;
    k_lo = 0; k_hi = K;
  } else {
    m_base = blockIdx.y * BM;
    m_end  = NTOK;
    k_lo = blockIdx.z * (K / KSPLIT);
    k_hi = k_lo + K / KSPLIT;
  }
  const float* W = W_base + (long)e * expert_stride;

  constexpr int LDT = 40;
  __shared__ __attribute__((aligned(16))) bf16 As[BM * LDT];
  __shared__ __attribute__((aligned(16))) bf16 Bs[BN * LDT];

  const int tid = threadIdx.x;
  const int wave = tid >> 6, lane = tid & 63;
  const int wm = wave >> 1, wn = wave & 1;   // wave: 32 rows x 64 cols
  f32x4 acc[2][4];
#pragma unroll
  for (int i = 0; i < 2; i++)
#pragma unroll
    for (int j = 0; j < 4; j++) acc[i][j] = f32x4{0.f, 0.f, 0.f, 0.f};

  const int aar = tid >> 2, aac = (tid & 3) * 8;  // A: 64 rows x 4 chunks of 8 bf16
  const int br  = tid >> 3, bc  = (tid & 7) * 4;  // B: 32 rows/pass x 8 float4

  for (int k0 = k_lo; k0 < k_hi; k0 += 32) {
    {  // A: bf16 16B copy (h_e is padded so tail-row reads are in-bounds)
      int4 v = *(const int4*)&Hin[(long)(m_base + aar) * K + k0 + aac];
      *(int4*)&As[aar * LDT + aac] = v;
    }
#pragma unroll
    for (int p = 0; p < 4; p++) {
      int r = p * 32 + br;
      float4 v = *(const float4*)&W[(long)(n0 + r) * K + k0 + bc];
      bf16* d = &Bs[r * LDT + bc];
      d[0] = (bf16)v.x; d[1] = (bf16)v.y; d[2] = (bf16)v.z; d[3] = (bf16)v.w;
    }
    __syncthreads();
    const int fr = lane & 15, fk = (lane >> 4) * 8;
    bf16x8 a[2], b[4];
#pragma unroll
    for (int i = 0; i < 2; i++)
      a[i] = *(const bf16x8*)&As[(wm * 32 + i * 16 + fr) * LDT + fk];
#pragma unroll
    for (int j = 0; j < 4; j++)
      b[j] = *(const bf16x8*)&Bs[(wn * 64 + j * 16 + fr) * LDT + fk];
#pragma unroll
    for (int i = 0; i < 2; i++)
#pragma unroll
      for (int j = 0; j < 4; j++)
        acc[i][j] = __builtin_amdgcn_mfma_f32_16x16x32_bf16(a[i], b[j], acc[i][j], 0, 0, 0);
    __syncthreads();
  }
#pragma unroll
  for (int i = 0; i < 2; i++)
#pragma unroll
    for (int j = 0; j < 4; j++)
#pragma unroll
      for (int r = 0; r < 4; r++) {
        int row = wm * 32 + i * 16 + (lane >> 4) * 4 + r;
        int grow = m_base + row;
        if (GROUPED && grow >= m_end) continue;
        int col = wn * 64 + j * 16 + (lane & 15);
        float s = scale[grow];
        int target = GROUPED ? s_tok[grow] : grow;
        atomicAdd(&Out[(long)target * HID + n0 + col], s * acc[i][j][r]);
      }
}

// ---------------------------------------------------------------------------
extern "C" void kernel_launch(void* const* d_in, const int* in_sizes, int n_in,
                              void* d_out, int out_size, void* d_ws, size_t ws_size,
                              hipStream_t stream)
{
  const float* x    = (const float*)d_in[0];
  const float* gw   = (const float*)d_in[1];
  const float* w1   = (const float*)d_in[2];
  const float* w2   = (const float*)d_in[3];
  const float* sguw = (const float*)d_in[4];
  const float* sdw  = (const float*)d_in[5];
  const float* sgw  = (const float*)d_in[6];
  float* out = (float*)d_out;

  char* ws = (char*)d_ws;
  size_t off = 0;
  auto alloc = [&](size_t bytes) {
    void* p = ws + off;
    off = (off + bytes + 255) & ~(size_t)255;
    return p;
  };
  float*  sg    = (float*)alloc(NTOK * 4);
  int2*   tki   = (int2*)alloc(NTOK * 8);
  float2* tkw   = (float2*)alloc(NTOK * 8);
  int*    offs  = (int*)alloc(64);
  int*    s_tok = (int*)alloc(NASSIGN * 4);
  float*  s_wgt = (float*)alloc(NASSIGN * 4);
  bf16*   h_sh  = (bf16*)alloc((size_t)NTOK * ISH * 2);
  bf16*   h_e   = (bf16*)alloc((size_t)(NASSIGN + 128) * IMOE * 2);  // pad: tail-row loads

  router_kernel<<<NTOK, 256, 0, stream>>>(x, gw, sgw, sg, tki, tkw);
  scatter_kernel<<<1, 256, 0, stream>>>(tki, tkw, offs, s_tok, s_wgt);
  hipMemsetAsync(d_out, 0, (size_t)out_size * 4, stream);

  // shared gate_up -> h_sh [1024, 5632] bf16
  gemm_gu<128, false><<<dim3(ISH / 64, NTOK / 128, 1), 256, 0, stream>>>(
      x, sguw, 0, (long)ISH * HID, HID, h_sh, ISH, nullptr, nullptr);
  // expert gate_up (grouped) -> h_e [2048, 1408] bf16 (expert-sorted rows)
  gemm_gu<64, true><<<dim3(IMOE / 64, 16, NEXP), 256, 0, stream>>>(
      x, w1, (long)2 * IMOE * HID, (long)IMOE * HID, HID, h_e, IMOE, offs, s_tok);
  // shared down (split-K=4): out += sg[t] * h_sh . sdw^T
  gemm_down<false, 4><<<dim3(HID / 128, NTOK / 64, 4), 256, 0, stream>>>(
      h_sh, ISH, sdw, 0, out, sg, nullptr, nullptr);
  // expert down (grouped): out[token] += wgt * h_e . w2[e]^T
  gemm_down<true, 1><<<dim3(HID / 128, 16, NEXP), 256, 0, stream>>>(
      h_e, IMOE, w2, (long)HID * IMOE, out, s_wgt, offs, s_tok);
}

// Round 2
// 822.365 us; speedup vs baseline: 1.0132x; 1.0132x over previous
//
#include <hip/hip_runtime.h>
#include <hip/hip_bf16.h>
#include <math.h>

// Problem constants
#define HID   2048
#define NEXP  8
#define IMOE  1408
#define ISH   5632
#define NTOK  1024
#define NASSIGN 2048   // NTOK * TOP_K

typedef __bf16 bf16;
typedef __bf16 bf16x8 __attribute__((ext_vector_type(8)));
typedef float  f32x4  __attribute__((ext_vector_type(4)));

__device__ inline bf16x8 cvt8(float4 a, float4 b) {
  bf16x8 r;
  r[0] = (bf16)a.x; r[1] = (bf16)a.y; r[2] = (bf16)a.z; r[3] = (bf16)a.w;
  r[4] = (bf16)b.x; r[5] = (bf16)b.y; r[6] = (bf16)b.z; r[7] = (bf16)b.w;
  return r;
}

// ---------------------------------------------------------------------------
// Router: logits = x @ gate_w^T (8), shared gate logit (1).
// top-2 of softmax renormalized == sigmoid(l0 - l1). One block per token.
// ---------------------------------------------------------------------------
__global__ __launch_bounds__(256) void router_kernel(
    const float* __restrict__ x, const float* __restrict__ gate_w,
    const float* __restrict__ sgate_w, float* __restrict__ sg,
    int2* __restrict__ tk_idx, float2* __restrict__ tk_w)
{
  const int t = blockIdx.x;
  const float* xr = x + (long)t * HID;
  float p[9];
#pragma unroll
  for (int i = 0; i < 9; i++) p[i] = 0.f;
  for (int c = threadIdx.x; c < HID; c += 256) {
    float xv = xr[c];
#pragma unroll
    for (int e = 0; e < 8; e++) p[e] += xv * gate_w[e * HID + c];
    p[8] += xv * sgate_w[c];
  }
#pragma unroll
  for (int i = 0; i < 9; i++)
    for (int off = 32; off > 0; off >>= 1)
      p[i] += __shfl_xor(p[i], off, 64);
  __shared__ float red[4][9];
  const int wave = threadIdx.x >> 6, lane = threadIdx.x & 63;
  if (lane == 0)
    for (int i = 0; i < 9; i++) red[wave][i] = p[i];
  __syncthreads();
  if (threadIdx.x == 0) {
    float l[9];
    for (int i = 0; i < 9; i++)
      l[i] = red[0][i] + red[1][i] + red[2][i] + red[3][i];
    int i0 = 0;
    for (int e = 1; e < 8; e++) if (l[e] > l[i0]) i0 = e;   // ties -> lowest idx
    int i1 = -1;
    for (int e = 0; e < 8; e++) {
      if (e == i0) continue;
      if (i1 < 0 || l[e] > l[i1]) i1 = e;
    }
    float w0 = 1.f / (1.f + __expf(l[i1] - l[i0]));
    tk_idx[t] = make_int2(i0, i1);
    tk_w[t]   = make_float2(w0, 1.f - w0);
    sg[t]     = 1.f / (1.f + __expf(-l[8]));
  }
}

// ---------------------------------------------------------------------------
// Scatter assignments (token,slot) into expert-sorted compact lists.
// ---------------------------------------------------------------------------
__global__ __launch_bounds__(256) void scatter_kernel(
    const int2* __restrict__ tk_idx, const float2* __restrict__ tk_w,
    int* __restrict__ offs, int* __restrict__ s_tok, float* __restrict__ s_wgt)
{
  __shared__ int cnt[8], pos[8];
  if (threadIdx.x < 8) cnt[threadIdx.x] = 0;
  __syncthreads();
  for (int a = threadIdx.x; a < NASSIGN; a += 256) {
    int2 ii = tk_idx[a >> 1];
    int e = (a & 1) ? ii.y : ii.x;
    atomicAdd(&cnt[e], 1);
  }
  __syncthreads();
  if (threadIdx.x == 0) {
    int s = 0;
    for (int e = 0; e < 8; e++) { offs[e] = s; pos[e] = s; s += cnt[e]; }
    offs[8] = s;
  }
  __syncthreads();
  for (int a = threadIdx.x; a < NASSIGN; a += 256) {
    int t = a >> 1;
    int2 ii = tk_idx[t];
    float2 ww = tk_w[t];
    int   e = (a & 1) ? ii.y : ii.x;
    float w = (a & 1) ? ww.y : ww.x;
    int pp = atomicAdd(&pos[e], 1);
    s_tok[pp] = t;
    s_wgt[pp] = w;
  }
}

// ---------------------------------------------------------------------------
// Fused gate_up GEMM + SiLU*mul. C[m,n] = silu(X.Wg^T) * (X.Wu^T)
// Software-pipelined: dbuf LDS, 1 barrier/step, reg prefetch overlapping MFMA.
// BM x 64 tile; 4 waves 2x2; BK=32; 16x16x32 bf16 MFMA.
// ---------------------------------------------------------------------------
template<int BM, bool GROUPED>
__global__ __launch_bounds__(256) void gemm_gu(
    const float* __restrict__ X,
    const float* __restrict__ Wg_base,
    long expert_stride, long up_off,
    bf16* __restrict__ Hout, int hstride,
    const int* __restrict__ offs, const int* __restrict__ s_tok,
    const float* __restrict__ zpad)
{
  static_assert(BM == 64 || BM == 128, "BM");
  constexpr int K = HID, NS = K / 32, LDT = 40;
  constexpr int APASS = BM / 64;
  const int n0 = blockIdx.x * 64;
  const int e  = GROUPED ? blockIdx.z : 0;
  int m_base, m_end;
  if (GROUPED) {
    m_base = offs[e] + blockIdx.y * BM;
    m_end  = offs[e + 1];
    if (m_base >= m_end) return;
  } else { m_base = blockIdx.y * BM; m_end = NTOK; }
  const float* Wg = Wg_base + (long)e * expert_stride;
  const float* Wu = Wg + up_off;

  __shared__ __attribute__((aligned(16))) bf16 As[2][BM * LDT];
  __shared__ __attribute__((aligned(16))) bf16 Bs[2][128 * LDT];

  const int tid  = threadIdx.x;
  const int crow = tid >> 2;          // 0..63
  const int ccol = (tid & 3) * 8;     // elem offset (8 per chunk)

  // per-thread source pointers (advance by 32 floats per step)
  const float* pa[APASS];
#pragma unroll
  for (int p = 0; p < APASS; p++) {
    int r = p * 64 + crow;
    if (GROUPED) {
      int gr = m_base + r;
      int tok = (gr < m_end) ? s_tok[gr] : -1;
      pa[p] = (tok >= 0) ? (X + (long)tok * K + ccol) : (zpad + ccol);
    } else {
      pa[p] = X + (long)(m_base + r) * K + ccol;
    }
  }
  const float* pb[2];
  pb[0] = Wg + (long)(n0 + crow) * K + ccol;
  pb[1] = Wu + (long)(n0 + crow) * K + ccol;

  const int wave = tid >> 6, lane = tid & 63;
  const int wm = wave >> 1, wn = wave & 1;
  constexpr int AF = BM / 32;
  f32x4 accg[AF][2], accu[AF][2];
#pragma unroll
  for (int i = 0; i < AF; i++)
#pragma unroll
    for (int j = 0; j < 2; j++) {
      accg[i][j] = f32x4{0.f, 0.f, 0.f, 0.f};
      accu[i][j] = f32x4{0.f, 0.f, 0.f, 0.f};
    }

  // prologue loads (tile 0)
  float4 va[APASS][2], vb[2][2];
#pragma unroll
  for (int p = 0; p < APASS; p++) {
    va[p][0] = *(const float4*)(pa[p]);
    va[p][1] = *(const float4*)(pa[p] + 4);
    pa[p] += 32;
  }
#pragma unroll
  for (int p = 0; p < 2; p++) {
    vb[p][0] = *(const float4*)(pb[p]);
    vb[p][1] = *(const float4*)(pb[p] + 4);
    pb[p] += 32;
  }

  const int fr = lane & 15, fk = (lane >> 4) * 8;

  for (int s = 0; s < NS; s++) {
    bf16* as = As[s & 1];
    bf16* bs = Bs[s & 1];
#pragma unroll
    for (int p = 0; p < APASS; p++)
      *(bf16x8*)&as[(p * 64 + crow) * LDT + ccol] = cvt8(va[p][0], va[p][1]);
#pragma unroll
    for (int p = 0; p < 2; p++)
      *(bf16x8*)&bs[(p * 64 + crow) * LDT + ccol] = cvt8(vb[p][0], vb[p][1]);
    __syncthreads();
    if (s + 1 < NS) {   // prefetch tile s+1: in flight across the MFMA phase
#pragma unroll
      for (int p = 0; p < APASS; p++) {
        va[p][0] = *(const float4*)(pa[p]);
        va[p][1] = *(const float4*)(pa[p] + 4);
        pa[p] += 32;
      }
#pragma unroll
      for (int p = 0; p < 2; p++) {
        vb[p][0] = *(const float4*)(pb[p]);
        vb[p][1] = *(const float4*)(pb[p] + 4);
        pb[p] += 32;
      }
    }
    bf16x8 a[AF], bg[2], bu[2];
#pragma unroll
    for (int i = 0; i < AF; i++)
      a[i] = *(const bf16x8*)&as[(wm * (AF * 16) + i * 16 + fr) * LDT + fk];
#pragma unroll
    for (int j = 0; j < 2; j++) {
      bg[j] = *(const bf16x8*)&bs[(wn * 32 + j * 16 + fr) * LDT + fk];
      bu[j] = *(const bf16x8*)&bs[(64 + wn * 32 + j * 16 + fr) * LDT + fk];
    }
#pragma unroll
    for (int i = 0; i < AF; i++)
#pragma unroll
      for (int j = 0; j < 2; j++) {
        accg[i][j] = __builtin_amdgcn_mfma_f32_16x16x32_bf16(a[i], bg[j], accg[i][j], 0, 0, 0);
        accu[i][j] = __builtin_amdgcn_mfma_f32_16x16x32_bf16(a[i], bu[j], accu[i][j], 0, 0, 0);
      }
  }
  // epilogue: h = silu(g) * u  (C/D: row=(lane>>4)*4+r, col=lane&15)
#pragma unroll
  for (int i = 0; i < AF; i++)
#pragma unroll
    for (int j = 0; j < 2; j++)
#pragma unroll
      for (int r = 0; r < 4; r++) {
        int row  = wm * (AF * 16) + i * 16 + (lane >> 4) * 4 + r;
        int grow = m_base + row;
        if (GROUPED && grow >= m_end) continue;
        int col = wn * 32 + j * 16 + (lane & 15);
        float g = accg[i][j][r], u = accu[i][j][r];
        float h = g / (1.f + __expf(-g)) * u;
        Hout[(long)grow * hstride + n0 + col] = (bf16)h;
      }
}

// ---------------------------------------------------------------------------
// Down GEMM: out[target(m), n] += scale(m) * (H . W^T)[m,n]
// Same pipeline structure. 64x128 tile, BK=32, atomicAdd epilogue.
// ---------------------------------------------------------------------------
template<bool GROUPED, int KSPLIT>
__global__ __launch_bounds__(256) void gemm_down(
    const bf16* __restrict__ Hin, int K,
    const float* __restrict__ W_base, long expert_stride,
    float* __restrict__ Out, const float* __restrict__ scale,
    const int* __restrict__ offs, const int* __restrict__ s_tok)
{
  constexpr int BM = 64, BN = 128, LDT = 40;
  const int n0 = blockIdx.x * BN;
  int e = 0, m_base, m_end, k_lo, k_hi;
  if (GROUPED) {
    e = blockIdx.z;
    m_base = offs[e] + blockIdx.y * BM;
    m_end  = offs[e + 1];
    if (m_base >= m_end) return;
    k_lo = 0; k_hi = K;
  } else {
    m_base = blockIdx.y * BM;
    m_end  = NTOK;
    k_lo = blockIdx.z * (K / KSPLIT);
    k_hi = k_lo + K / KSPLIT;
  }
  const int NS = (k_hi - k_lo) / 32;
  const float* W = W_base + (long)e * expert_stride;

  __shared__ __attribute__((aligned(16))) bf16 As[2][BM * LDT];
  __shared__ __attribute__((aligned(16))) bf16 Bs[2][BN * LDT];

  const int tid  = threadIdx.x;
  const int crow = tid >> 2;
  const int ccol = (tid & 3) * 8;

  const bf16*  pA    = Hin + (long)(m_base + crow) * K + k_lo + ccol;
  const float* pb[2] = { W + (long)(n0 + crow) * K + k_lo + ccol,
                         W + (long)(n0 + 64 + crow) * K + k_lo + ccol };

  const int wave = tid >> 6, lane = tid & 63;
  const int wm = wave >> 1, wn = wave & 1;
  f32x4 acc[2][4];
#pragma unroll
  for (int i = 0; i < 2; i++)
#pragma unroll
    for (int j = 0; j < 4; j++) acc[i][j] = f32x4{0.f, 0.f, 0.f, 0.f};

  int4   vA;
  float4 vb[2][2];
  vA = *(const int4*)pA; pA += 32;
#pragma unroll
  for (int p = 0; p < 2; p++) {
    vb[p][0] = *(const float4*)(pb[p]);
    vb[p][1] = *(const float4*)(pb[p] + 4);
    pb[p] += 32;
  }

  const int fr = lane & 15, fk = (lane >> 4) * 8;

  for (int s = 0; s < NS; s++) {
    bf16* as = As[s & 1];
    bf16* bs = Bs[s & 1];
    *(int4*)&as[crow * LDT + ccol] = vA;
#pragma unroll
    for (int p = 0; p < 2; p++)
      *(bf16x8*)&bs[(p * 64 + crow) * LDT + ccol] = cvt8(vb[p][0], vb[p][1]);
    __syncthreads();
    if (s + 1 < NS) {
      vA = *(const int4*)pA; pA += 32;
#pragma unroll
      for (int p = 0; p < 2; p++) {
        vb[p][0] = *(const float4*)(pb[p]);
        vb[p][1] = *(const float4*)(pb[p] + 4);
        pb[p] += 32;
      }
    }
    bf16x8 a[2], b[4];
#pragma unroll
    for (int i = 0; i < 2; i++)
      a[i] = *(const bf16x8*)&as[(wm * 32 + i * 16 + fr) * LDT + fk];
#pragma unroll
    for (int j = 0; j < 4; j++)
      b[j] = *(const bf16x8*)&bs[(wn * 64 + j * 16 + fr) * LDT + fk];
#pragma unroll
    for (int i = 0; i < 2; i++)
#pragma unroll
      for (int j = 0; j < 4; j++)
        acc[i][j] = __builtin_amdgcn_mfma_f32_16x16x32_bf16(a[i], b[j], acc[i][j], 0, 0, 0);
  }
#pragma unroll
  for (int i = 0; i < 2; i++)
#pragma unroll
    for (int j = 0; j < 4; j++)
#pragma unroll
      for (int r = 0; r < 4; r++) {
        int row  = wm * 32 + i * 16 + (lane >> 4) * 4 + r;
        int grow = m_base + row;
        if (GROUPED && grow >= m_end) continue;
        int col = wn * 64 + j * 16 + (lane & 15);
        float sc = scale[grow];
        int target = GROUPED ? s_tok[grow] : grow;
        atomicAdd(&Out[(long)target * HID + n0 + col], sc * acc[i][j][r]);
      }
}

// ---------------------------------------------------------------------------
extern "C" void kernel_launch(void* const* d_in, const int* in_sizes, int n_in,
                              void* d_out, int out_size, void* d_ws, size_t ws_size,
                              hipStream_t stream)
{
  const float* x    = (const float*)d_in[0];
  const float* gw   = (const float*)d_in[1];
  const float* w1   = (const float*)d_in[2];
  const float* w2   = (const float*)d_in[3];
  const float* sguw = (const float*)d_in[4];
  const float* sdw  = (const float*)d_in[5];
  const float* sgw  = (const float*)d_in[6];
  float* out = (float*)d_out;

  char* ws = (char*)d_ws;
  size_t off = 0;
  auto alloc = [&](size_t bytes) {
    void* p = ws + off;
    off = (off + bytes + 255) & ~(size_t)255;
    return p;
  };
  float*  sg    = (float*)alloc(NTOK * 4);
  int2*   tki   = (int2*)alloc(NTOK * 8);
  float2* tkw   = (float2*)alloc(NTOK * 8);
  int*    offs  = (int*)alloc(64);
  int*    s_tok = (int*)alloc(NASSIGN * 4);
  float*  s_wgt = (float*)alloc(NASSIGN * 4);
  float*  zpad  = (float*)alloc((HID + 64) * 4);                     // zeroed pad rows
  bf16*   h_sh  = (bf16*)alloc((size_t)NTOK * ISH * 2);
  bf16*   h_e   = (bf16*)alloc((size_t)(NASSIGN + 128) * IMOE * 2);  // pad: tail rows

  hipMemsetAsync(zpad, 0, (HID + 64) * 4, stream);
  hipMemsetAsync(d_out, 0, (size_t)out_size * 4, stream);
  router_kernel<<<NTOK, 256, 0, stream>>>(x, gw, sgw, sg, tki, tkw);
  scatter_kernel<<<1, 256, 0, stream>>>(tki, tkw, offs, s_tok, s_wgt);

  // shared gate_up -> h_sh [1024, 5632] bf16
  gemm_gu<128, false><<<dim3(ISH / 64, NTOK / 128, 1), 256, 0, stream>>>(
      x, sguw, 0, (long)ISH * HID, h_sh, ISH, nullptr, nullptr, zpad);
  // expert gate_up (grouped) -> h_e (expert-sorted rows)
  gemm_gu<64, true><<<dim3(IMOE / 64, 16, NEXP), 256, 0, stream>>>(
      x, w1, (long)2 * IMOE * HID, (long)IMOE * HID, h_e, IMOE, offs, s_tok, zpad);
  // shared down (split-K=4): out += sg[t] * h_sh . sdw^T
  gemm_down<false, 4><<<dim3(HID / 128, NTOK / 64, 4), 256, 0, stream>>>(
      h_sh, ISH, sdw, 0, out, sg, nullptr, nullptr);
  // expert down (grouped): out[token] += wgt * h_e . w2[e]^T
  gemm_down<true, 1><<<dim3(HID / 128, 16, NEXP), 256, 0, stream>>>(
      h_e, IMOE, w2, (long)HID * IMOE, out, s_wgt, offs, s_tok);
}

// Round 3
// 733.278 us; speedup vs baseline: 1.1363x; 1.1215x over previous
//
#include <hip/hip_runtime.h>
#include <hip/hip_bf16.h>
#include <math.h>

// Problem constants
#define HID   2048
#define NEXP  8
#define IMOE  1408
#define ISH   5632
#define NTOK  1024
#define NASSIGN 2048   // NTOK * TOP_K

typedef __bf16 bf16;
typedef __bf16 bf16x8 __attribute__((ext_vector_type(8)));
typedef float  f32x4  __attribute__((ext_vector_type(4)));

__device__ inline bf16x8 cvt8(float4 a, float4 b) {
  bf16x8 r;
  r[0] = (bf16)a.x; r[1] = (bf16)a.y; r[2] = (bf16)a.z; r[3] = (bf16)a.w;
  r[4] = (bf16)b.x; r[5] = (bf16)b.y; r[6] = (bf16)b.z; r[7] = (bf16)b.w;
  return r;
}

// async 16B/lane global->LDS. lptr must be wave-uniform; HW adds lane*16.
__device__ inline void async16(const bf16* g, bf16* l) {
  __builtin_amdgcn_global_load_lds(
      (const __attribute__((address_space(1))) void*)g,
      (__attribute__((address_space(3))) void*)l, 16, 0, 0);
}

// ---------------------------------------------------------------------------
// fp32 -> bf16 weight/x conversion (single streaming pass)
// segments (8-elem chunks): x 262144 | w1 5767168 | w2 2883584 | sgu 2883584 | sdw 1441792
// ---------------------------------------------------------------------------
#define CVT_P0 262144L
#define CVT_P1 6029312L
#define CVT_P2 8912896L
#define CVT_P3 11796480L
#define CVT_P4 13238272L   // total chunks; grid = CVT_P4/256 = 51712

__global__ __launch_bounds__(256) void convert_kernel(
    const float* __restrict__ x, const float* __restrict__ w1,
    const float* __restrict__ w2, const float* __restrict__ sgu,
    const float* __restrict__ sdw,
    bf16* __restrict__ xb, bf16* __restrict__ w1b, bf16* __restrict__ w2b,
    bf16* __restrict__ sgub, bf16* __restrict__ sdwb)
{
  long g = (long)blockIdx.x * 256 + threadIdx.x;
  const float* s; bf16* d; long off;
  if      (g < CVT_P0) { s = x;   d = xb;   off = g; }
  else if (g < CVT_P1) { s = w1;  d = w1b;  off = g - CVT_P0; }
  else if (g < CVT_P2) { s = w2;  d = w2b;  off = g - CVT_P1; }
  else if (g < CVT_P3) { s = sgu; d = sgub; off = g - CVT_P2; }
  else                 { s = sdw; d = sdwb; off = g - CVT_P3; }
  long e = off * 8;
  float4 a = *(const float4*)(s + e);
  float4 b = *(const float4*)(s + e + 4);
  *(bf16x8*)(d + e) = cvt8(a, b);
}

// ---------------------------------------------------------------------------
// Router (fp32): top-2 renormalized = sigmoid(l0-l1); shared sigmoid gate.
// ---------------------------------------------------------------------------
__global__ __launch_bounds__(256) void router_kernel(
    const float* __restrict__ x, const float* __restrict__ gate_w,
    const float* __restrict__ sgate_w, float* __restrict__ sg,
    int2* __restrict__ tk_idx, float2* __restrict__ tk_w)
{
  const int t = blockIdx.x;
  const float* xr = x + (long)t * HID;
  float p[9];
#pragma unroll
  for (int i = 0; i < 9; i++) p[i] = 0.f;
  for (int c = threadIdx.x; c < HID; c += 256) {
    float xv = xr[c];
#pragma unroll
    for (int e = 0; e < 8; e++) p[e] += xv * gate_w[e * HID + c];
    p[8] += xv * sgate_w[c];
  }
#pragma unroll
  for (int i = 0; i < 9; i++)
    for (int off = 32; off > 0; off >>= 1)
      p[i] += __shfl_xor(p[i], off, 64);
  __shared__ float red[4][9];
  const int wave = threadIdx.x >> 6, lane = threadIdx.x & 63;
  if (lane == 0)
    for (int i = 0; i < 9; i++) red[wave][i] = p[i];
  __syncthreads();
  if (threadIdx.x == 0) {
    float l[9];
    for (int i = 0; i < 9; i++)
      l[i] = red[0][i] + red[1][i] + red[2][i] + red[3][i];
    int i0 = 0;
    for (int e = 1; e < 8; e++) if (l[e] > l[i0]) i0 = e;
    int i1 = -1;
    for (int e = 0; e < 8; e++) {
      if (e == i0) continue;
      if (i1 < 0 || l[e] > l[i1]) i1 = e;
    }
    float w0 = 1.f / (1.f + __expf(l[i1] - l[i0]));
    tk_idx[t] = make_int2(i0, i1);
    tk_w[t]   = make_float2(w0, 1.f - w0);
    sg[t]     = 1.f / (1.f + __expf(-l[8]));
  }
}

__global__ __launch_bounds__(256) void scatter_kernel(
    const int2* __restrict__ tk_idx, const float2* __restrict__ tk_w,
    int* __restrict__ offs, int* __restrict__ s_tok, float* __restrict__ s_wgt)
{
  __shared__ int cnt[8], pos[8];
  if (threadIdx.x < 8) cnt[threadIdx.x] = 0;
  __syncthreads();
  for (int a = threadIdx.x; a < NASSIGN; a += 256) {
    int2 ii = tk_idx[a >> 1];
    int e = (a & 1) ? ii.y : ii.x;
    atomicAdd(&cnt[e], 1);
  }
  __syncthreads();
  if (threadIdx.x == 0) {
    int s = 0;
    for (int e = 0; e < 8; e++) { offs[e] = s; pos[e] = s; s += cnt[e]; }
    offs[8] = s;
  }
  __syncthreads();
  for (int a = threadIdx.x; a < NASSIGN; a += 256) {
    int t = a >> 1;
    int2 ii = tk_idx[t];
    float2 ww = tk_w[t];
    int   e = (a & 1) ? ii.y : ii.x;
    float w = (a & 1) ? ww.y : ww.x;
    int pp = atomicAdd(&pos[e], 1);
    s_tok[pp] = t;
    s_wgt[pp] = w;
  }
}

// ---------------------------------------------------------------------------
// Fused gate_up GEMM + SiLU*mul (m97-style): bf16 global_load_lds width=16,
// single LDS buffer, 2 barriers/step, BK=32, 16x16x32 MFMA.
// LDS tiles unpadded [rows][32] bf16; 16B chunks XOR-swizzled by (row&3)
// on the GLOBAL side so frag ds_read_b128 is conflict-free.
// B tile = 128 rows: [0..63]=gate, [64..127]=up for 64 output h-cols.
// ---------------------------------------------------------------------------
template<int BM, bool GROUPED>
__global__ __launch_bounds__(256) void gemm_gu(
    const bf16* __restrict__ X,
    const bf16* __restrict__ Wg_base, long expert_stride, long up_off,
    bf16* __restrict__ Hout, int hstride,
    const int* __restrict__ offs, const int* __restrict__ s_tok,
    const bf16* __restrict__ zpad)
{
  static_assert(BM == 64 || BM == 128, "BM");
  constexpr int K = HID, NS = K / 32;
  constexpr int AIP = BM / 64;   // A staging insts per wave
  constexpr int AF  = BM / 32;   // A frags per wave
  const int n0 = blockIdx.x * 64;
  const int e  = GROUPED ? blockIdx.z : 0;
  int m_base, m_end;
  if (GROUPED) {
    m_base = offs[e] + blockIdx.y * BM;
    m_end  = offs[e + 1];
    if (m_base >= m_end) return;
  } else { m_base = blockIdx.y * BM; m_end = NTOK; }
  const bf16* Wg = Wg_base + (long)e * expert_stride;

  __shared__ __attribute__((aligned(16))) bf16 As[BM * 32];
  __shared__ __attribute__((aligned(16))) bf16 Bs[128 * 32];

  const int tid = threadIdx.x, wave = tid >> 6, lane = tid & 63;

  // staging pointers: inst covers 16 rows; lane -> (row=l>>2, pos=l&3),
  // fetch global chunk g = pos ^ (row&3)  (swizzle)
  const bf16* pa[AIP]; bf16* la[AIP];
#pragma unroll
  for (int q = 0; q < AIP; q++) {
    int ia  = wave * AIP + q;
    int rl  = ia * 16 + (lane >> 2);
    int gch = (lane & 3) ^ (rl & 3);
    const bf16* src;
    if (GROUPED) {
      int gr  = m_base + rl;
      int tok = (gr < m_end) ? s_tok[gr] : -1;
      src = (tok >= 0) ? X + (long)tok * K : zpad;
    } else src = X + (long)(m_base + rl) * K;
    pa[q] = src + gch * 8;
    la[q] = As + ia * 512;
  }
  const bf16* pb[2]; bf16* lb[2];
#pragma unroll
  for (int q = 0; q < 2; q++) {
    int ib  = wave * 2 + q;
    int rl  = ib * 16 + (lane >> 2);
    int gch = (lane & 3) ^ (rl & 3);
    const bf16* src = (rl < 64) ? Wg + (long)(n0 + rl) * K
                                : Wg + up_off + (long)(n0 + rl - 64) * K;
    pb[q] = src + gch * 8;
    lb[q] = Bs + ib * 512;
  }

  const int wm = wave >> 1, wn = wave & 1;
  f32x4 accg[AF][2], accu[AF][2];
#pragma unroll
  for (int i = 0; i < AF; i++)
#pragma unroll
    for (int j = 0; j < 2; j++) {
      accg[i][j] = f32x4{0.f, 0.f, 0.f, 0.f};
      accu[i][j] = f32x4{0.f, 0.f, 0.f, 0.f};
    }

  const int fr = lane & 15, cch = lane >> 4;   // frag row, k-chunk

  for (int s = 0; s < NS; s++) {
    __syncthreads();            // previous consumers done with LDS
#pragma unroll
    for (int q = 0; q < AIP; q++) { async16(pa[q], la[q]); pa[q] += 32; }
#pragma unroll
    for (int q = 0; q < 2;   q++) { async16(pb[q], lb[q]); pb[q] += 32; }
    asm volatile("s_waitcnt vmcnt(0)" ::: "memory");
    __syncthreads();            // staged tile visible to all waves

    bf16x8 a[AF], bg[2], bu[2];
#pragma unroll
    for (int i = 0; i < AF; i++) {
      int ar = wm * (AF * 16) + i * 16 + fr;
      a[i] = *(const bf16x8*)&As[ar * 32 + ((cch ^ (ar & 3)) * 8)];
    }
#pragma unroll
    for (int j = 0; j < 2; j++) {
      int br = wn * 32 + j * 16 + fr;
      int ur = 64 + br;
      bg[j] = *(const bf16x8*)&Bs[br * 32 + ((cch ^ (br & 3)) * 8)];
      bu[j] = *(const bf16x8*)&Bs[ur * 32 + ((cch ^ (ur & 3)) * 8)];
    }
#pragma unroll
    for (int i = 0; i < AF; i++)
#pragma unroll
      for (int j = 0; j < 2; j++) {
        accg[i][j] = __builtin_amdgcn_mfma_f32_16x16x32_bf16(a[i], bg[j], accg[i][j], 0, 0, 0);
        accu[i][j] = __builtin_amdgcn_mfma_f32_16x16x32_bf16(a[i], bu[j], accu[i][j], 0, 0, 0);
      }
  }
  // epilogue: h = silu(g)*u  (C/D: row=(lane>>4)*4+r, col=lane&15)
#pragma unroll
  for (int i = 0; i < AF; i++)
#pragma unroll
    for (int j = 0; j < 2; j++)
#pragma unroll
      for (int r = 0; r < 4; r++) {
        int row  = wm * (AF * 16) + i * 16 + (lane >> 4) * 4 + r;
        int grow = m_base + row;
        if (GROUPED && grow >= m_end) continue;
        int col = wn * 32 + j * 16 + (lane & 15);
        float g = accg[i][j][r], u = accu[i][j][r];
        float h = g / (1.f + __expf(-g)) * u;
        Hout[(long)grow * hstride + n0 + col] = (bf16)h;
      }
}

// ---------------------------------------------------------------------------
// Down GEMM: out[target(m), n] += scale(m) * (H . W^T)[m,n]
// Same m97 staging. BM x 128 tile. atomicAdd fp32 epilogue.
// GROUPED: blockIdx.z = e*KSPLIT + ks.   !GROUPED: blockIdx.z = ks.
// ---------------------------------------------------------------------------
template<int BM, bool GROUPED, int KSPLIT>
__global__ __launch_bounds__(256) void gemm_down(
    const bf16* __restrict__ Hin, int K,
    const bf16* __restrict__ W_base, long expert_stride,
    float* __restrict__ Out, const float* __restrict__ scale,
    const int* __restrict__ offs, const int* __restrict__ s_tok)
{
  static_assert(BM == 64 || BM == 128, "BM");
  constexpr int AIP = BM / 64, AF = BM / 32;
  const int n0 = blockIdx.x * 128;
  int e = 0, ks, m_base, m_end;
  if (GROUPED) {
    e  = blockIdx.z / KSPLIT;
    ks = blockIdx.z % KSPLIT;
    m_base = offs[e] + blockIdx.y * BM;
    m_end  = offs[e + 1];
    if (m_base >= m_end) return;
  } else {
    ks = blockIdx.z;
    m_base = blockIdx.y * BM;
    m_end  = NTOK;
  }
  const int k_lo = ks * (K / KSPLIT);
  const int NS   = (K / KSPLIT) / 32;
  const bf16* W = W_base + (long)e * expert_stride;

  __shared__ __attribute__((aligned(16))) bf16 As[BM * 32];
  __shared__ __attribute__((aligned(16))) bf16 Bs[128 * 32];

  const int tid = threadIdx.x, wave = tid >> 6, lane = tid & 63;

  const bf16* pa[AIP]; bf16* la[AIP];
#pragma unroll
  for (int q = 0; q < AIP; q++) {
    int ia  = wave * AIP + q;
    int rl  = ia * 16 + (lane >> 2);
    int gch = (lane & 3) ^ (rl & 3);
    pa[q] = Hin + (long)(m_base + rl) * K + k_lo + gch * 8;  // rows compact; tail pad ok
    la[q] = As + ia * 512;
  }
  const bf16* pb[2]; bf16* lb[2];
#pragma unroll
  for (int q = 0; q < 2; q++) {
    int ib  = wave * 2 + q;
    int rl  = ib * 16 + (lane >> 2);
    int gch = (lane & 3) ^ (rl & 3);
    pb[q] = W + (long)(n0 + rl) * K + k_lo + gch * 8;
    lb[q] = Bs + ib * 512;
  }

  const int wm = wave >> 1, wn = wave & 1;
  f32x4 acc[AF][4];
#pragma unroll
  for (int i = 0; i < AF; i++)
#pragma unroll
    for (int j = 0; j < 4; j++) acc[i][j] = f32x4{0.f, 0.f, 0.f, 0.f};

  const int fr = lane & 15, cch = lane >> 4;

  for (int s = 0; s < NS; s++) {
    __syncthreads();
#pragma unroll
    for (int q = 0; q < AIP; q++) { async16(pa[q], la[q]); pa[q] += 32; }
#pragma unroll
    for (int q = 0; q < 2;   q++) { async16(pb[q], lb[q]); pb[q] += 32; }
    asm volatile("s_waitcnt vmcnt(0)" ::: "memory");
    __syncthreads();

    bf16x8 a[AF], b[4];
#pragma unroll
    for (int i = 0; i < AF; i++) {
      int ar = wm * (AF * 16) + i * 16 + fr;
      a[i] = *(const bf16x8*)&As[ar * 32 + ((cch ^ (ar & 3)) * 8)];
    }
#pragma unroll
    for (int j = 0; j < 4; j++) {
      int br = wn * 64 + j * 16 + fr;
      b[j] = *(const bf16x8*)&Bs[br * 32 + ((cch ^ (br & 3)) * 8)];
    }
#pragma unroll
    for (int i = 0; i < AF; i++)
#pragma unroll
      for (int j = 0; j < 4; j++)
        acc[i][j] = __builtin_amdgcn_mfma_f32_16x16x32_bf16(a[i], b[j], acc[i][j], 0, 0, 0);
  }
#pragma unroll
  for (int i = 0; i < AF; i++)
#pragma unroll
    for (int j = 0; j < 4; j++)
#pragma unroll
      for (int r = 0; r < 4; r++) {
        int row  = wm * (AF * 16) + i * 16 + (lane >> 4) * 4 + r;
        int grow = m_base + row;
        if (GROUPED && grow >= m_end) continue;
        int col = wn * 64 + j * 16 + (lane & 15);
        float sc = scale[grow];
        int target = GROUPED ? s_tok[grow] : grow;
        atomicAdd(&Out[(long)target * HID + n0 + col], sc * acc[i][j][r]);
      }
}

// ---------------------------------------------------------------------------
extern "C" void kernel_launch(void* const* d_in, const int* in_sizes, int n_in,
                              void* d_out, int out_size, void* d_ws, size_t ws_size,
                              hipStream_t stream)
{
  const float* x    = (const float*)d_in[0];
  const float* gw   = (const float*)d_in[1];
  const float* w1   = (const float*)d_in[2];
  const float* w2   = (const float*)d_in[3];
  const float* sguw = (const float*)d_in[4];
  const float* sdw  = (const float*)d_in[5];
  const float* sgw  = (const float*)d_in[6];
  float* out = (float*)d_out;

  char* ws = (char*)d_ws;
  size_t off = 0;
  auto alloc = [&](size_t bytes) {
    void* p = ws + off;
    off = (off + bytes + 255) & ~(size_t)255;
    return p;
  };
  float*  sg    = (float*)alloc(NTOK * 4);
  int2*   tki   = (int2*)alloc(NTOK * 8);
  float2* tkw   = (float2*)alloc(NTOK * 8);
  int*    offs  = (int*)alloc(64);
  int*    s_tok = (int*)alloc(NASSIGN * 4);
  float*  s_wgt = (float*)alloc(NASSIGN * 4);
  bf16*   zpadb = (bf16*)alloc((HID + 64) * 2);
  bf16*   xb    = (bf16*)alloc((size_t)NTOK * HID * 2);
  bf16*   w1b   = (bf16*)alloc((size_t)NEXP * 2 * IMOE * HID * 2);
  bf16*   w2b   = (bf16*)alloc((size_t)NEXP * HID * IMOE * 2);
  bf16*   sgub  = (bf16*)alloc((size_t)2 * ISH * HID * 2);
  bf16*   sdwb  = (bf16*)alloc((size_t)HID * ISH * 2);
  bf16*   h_sh  = (bf16*)alloc((size_t)NTOK * ISH * 2);
  bf16*   h_e   = (bf16*)alloc((size_t)(NASSIGN + 64) * IMOE * 2);  // pad tail rows

  hipMemsetAsync(zpadb, 0, (HID + 64) * 2, stream);
  hipMemsetAsync(d_out, 0, (size_t)out_size * 4, stream);
  router_kernel<<<NTOK, 256, 0, stream>>>(x, gw, sgw, sg, tki, tkw);
  scatter_kernel<<<1, 256, 0, stream>>>(tki, tkw, offs, s_tok, s_wgt);
  convert_kernel<<<51712, 256, 0, stream>>>(x, w1, w2, sguw, sdw,
                                            xb, w1b, w2b, sgub, sdwb);

  // shared gate_up -> h_sh [1024, 5632]
  gemm_gu<128, false><<<dim3(ISH / 64, NTOK / 128, 1), 256, 0, stream>>>(
      xb, sgub, 0, (long)ISH * HID, h_sh, ISH, nullptr, nullptr, zpadb);
  // expert gate_up (grouped) -> h_e (expert-sorted compact rows)
  gemm_gu<64, true><<<dim3(IMOE / 64, 16, NEXP), 256, 0, stream>>>(
      xb, w1b, (long)2 * IMOE * HID, (long)IMOE * HID, h_e, IMOE, offs, s_tok, zpadb);
  // shared down (split-K=8): out += sg[t] * h_sh . sdw^T
  gemm_down<128, false, 8><<<dim3(HID / 128, NTOK / 128, 8), 256, 0, stream>>>(
      h_sh, ISH, sdwb, 0, out, sg, nullptr, nullptr);
  // expert down (grouped, split-K=2): out[token] += wgt * h_e . w2[e]^T
  gemm_down<64, true, 2><<<dim3(HID / 128, 16, NEXP * 2), 256, 0, stream>>>(
      h_e, IMOE, w2b, (long)HID * IMOE, out, s_wgt, offs, s_tok);
}